// Round 1
// baseline (2853.694 us; speedup 1.0000x reference)
//
#include <hip/hip_runtime.h>
#include <hip/hip_bf16.h>
#include <math.h>

#define D_MODEL 1024
#define N_HEADS 16
#define HD 64
#define BB 2
#define TT 2048

// ---------------------------------------------------------------------------
// C[M,N] = A[M,K] @ W[K,N] + bias    (fp32, 64x64 tile, BK=16, 256 threads)
// ---------------------------------------------------------------------------
__global__ __launch_bounds__(256) void gemm_bias_kernel(
    const float* __restrict__ A, const float* __restrict__ W,
    const float* __restrict__ bias, float* __restrict__ C,
    int M, int N, int K)
{
    __shared__ float As[16][64];   // As[k][m]  (A tile stored transposed)
    __shared__ float Ws[16][64];   // Ws[k][n]

    const int tid  = threadIdx.x;
    const int tx   = tid & 15;          // 0..15 -> 4 cols each
    const int ty   = tid >> 4;          // 0..15 -> 4 rows each
    const int row0 = blockIdx.y * 64;
    const int col0 = blockIdx.x * 64;

    // staging index maps
    const int aRow = tid >> 2;          // 0..63
    const int aK   = (tid & 3) << 2;    // 0,4,8,12
    const int wK   = tid >> 4;          // 0..15
    const int wCol = (tid & 15) << 2;   // 0..60

    float acc[4][4] = {};

    for (int kb = 0; kb < K; kb += 16) {
        float4 av = *(const float4*)(A + (size_t)(row0 + aRow) * K + kb + aK);
        float4 wv = *(const float4*)(W + (size_t)(kb + wK) * N + col0 + wCol);
        As[aK + 0][aRow] = av.x;
        As[aK + 1][aRow] = av.y;
        As[aK + 2][aRow] = av.z;
        As[aK + 3][aRow] = av.w;
        *(float4*)&Ws[wK][wCol] = wv;
        __syncthreads();
#pragma unroll
        for (int k = 0; k < 16; ++k) {
            float4 a = *(const float4*)&As[k][ty << 2];
            float4 b = *(const float4*)&Ws[k][tx << 2];
            acc[0][0] += a.x * b.x; acc[0][1] += a.x * b.y;
            acc[0][2] += a.x * b.z; acc[0][3] += a.x * b.w;
            acc[1][0] += a.y * b.x; acc[1][1] += a.y * b.y;
            acc[1][2] += a.y * b.z; acc[1][3] += a.y * b.w;
            acc[2][0] += a.z * b.x; acc[2][1] += a.z * b.y;
            acc[2][2] += a.z * b.z; acc[2][3] += a.z * b.w;
            acc[3][0] += a.w * b.x; acc[3][1] += a.w * b.y;
            acc[3][2] += a.w * b.z; acc[3][3] += a.w * b.w;
        }
        __syncthreads();
    }

    float4 bv = *(const float4*)(bias + col0 + (tx << 2));
#pragma unroll
    for (int i = 0; i < 4; ++i) {
        float4 out;
        out.x = acc[i][0] + bv.x;
        out.y = acc[i][1] + bv.y;
        out.z = acc[i][2] + bv.z;
        out.w = acc[i][3] + bv.w;
        *(float4*)(C + (size_t)(row0 + (ty << 2) + i) * N + col0 + (tx << 2)) = out;
    }
}

// ---------------------------------------------------------------------------
// Causal flash attention, fp32. One wave per query row, 8 rows per block.
// Q,K,V layout: [B*T, D_MODEL] with head h occupying cols h*64..h*64+63.
// ---------------------------------------------------------------------------
__global__ __launch_bounds__(512) void attn_kernel(
    const float* __restrict__ Q, const float* __restrict__ K,
    const float* __restrict__ V, float* __restrict__ O)
{
    __shared__ float Kt[64][64];   // Kt[j][s]  (transposed K chunk)
    __shared__ float Vs[64][64];   // Vs[s][j]
    __shared__ float q_s[8][64];

    const int tid  = threadIdx.x;
    const int lane = tid & 63;
    const int w    = tid >> 6;               // wave 0..7
    const int row0 = blockIdx.x << 3;        // first of 8 rows, same (b,h)
    const int row  = row0 + w;               // row = (b*H + h)*T + t
    const int t    = row & (TT - 1);
    const int tmax = (row0 & (TT - 1)) + 7;

    const int bu = row0 >> 15;               // / (H*T) = / 32768
    const int hu = (row0 >> 11) & (N_HEADS - 1);

    const float* Kb = K + (size_t)bu * TT * D_MODEL + hu * HD;
    const float* Vb = V + (size_t)bu * TT * D_MODEL + hu * HD;

    const float qv = Q[(size_t)(bu * TT + t) * D_MODEL + hu * HD + lane] * 0.125f;
    q_s[w][lane] = qv;

    float m = -1e30f, l = 0.f, o = 0.f;
    const int nch = (tmax >> 6) + 1;

    for (int c = 0; c < nch; ++c) {
        const int s0 = c << 6;
        __syncthreads();   // protect LDS from previous iteration's readers
#pragma unroll
        for (int r = 0; r < 2; ++r) {
            int f    = tid + (r << 9);       // 0..1023 float4-slots
            int srow = f >> 4;               // 0..63
            int j4   = (f & 15) << 2;        // 0..60
            float4 kv = *(const float4*)(Kb + (size_t)(s0 + srow) * D_MODEL + j4);
            float4 vv = *(const float4*)(Vb + (size_t)(s0 + srow) * D_MODEL + j4);
            Kt[j4 + 0][srow] = kv.x;
            Kt[j4 + 1][srow] = kv.y;
            Kt[j4 + 2][srow] = kv.z;
            Kt[j4 + 3][srow] = kv.w;
            *(float4*)&Vs[srow][j4] = vv;
        }
        __syncthreads();

        // phase 1: lane computes score for key s0+lane
        const int s = s0 + lane;
        float sc = -1e30f;
        if (s <= t) {
            float acc = 0.f;
#pragma unroll
            for (int j = 0; j < 64; ++j)
                acc += q_s[w][j] * Kt[j][lane];
            sc = acc;
        }

        // online softmax update (wave-wide)
        float cm = sc;
#pragma unroll
        for (int off = 32; off > 0; off >>= 1)
            cm = fmaxf(cm, __shfl_xor(cm, off, 64));
        const float m_new = fmaxf(m, cm);
        const float alpha = __expf(m - m_new);
        const float p     = __expf(sc - m_new);
        float ps = p;
#pragma unroll
        for (int off = 32; off > 0; off >>= 1)
            ps += __shfl_xor(ps, off, 64);
        l = l * alpha + ps;
        o *= alpha;

        // phase 2: o_j += sum_i p_i * V[i][j]   (lane owns dim j = lane)
#pragma unroll
        for (int i = 0; i < 64; ++i) {
            float pi = __shfl(p, i, 64);
            o += pi * Vs[i][lane];
        }
        m = m_new;
    }

    O[(size_t)(bu * TT + t) * D_MODEL + hu * HD + lane] = o / l;
}

// ---------------------------------------------------------------------------
extern "C" void kernel_launch(void* const* d_in, const int* in_sizes, int n_in,
                              void* d_out, int out_size, void* d_ws, size_t ws_size,
                              hipStream_t stream) {
    const float* x  = (const float*)d_in[0];
    // d_in[1] = mask (pure causal; handled analytically)
    const float* Wq = (const float*)d_in[2];
    const float* bq = (const float*)d_in[3];
    const float* Wk = (const float*)d_in[4];
    const float* bk = (const float*)d_in[5];
    const float* Wv = (const float*)d_in[6];
    const float* bv = (const float*)d_in[7];
    const float* Wo = (const float*)d_in[8];
    const float* bo = (const float*)d_in[9];
    float* out = (float*)d_out;

    float* ws = (float*)d_ws;
    const size_t NTD = (size_t)BB * TT * D_MODEL;   // 4,194,304 elems = 16 MiB
    float* Qw = ws;
    float* Kw = ws + NTD;
    float* Vw = ws + 2 * NTD;
    float* Aw = ws + 3 * NTD;

    const int M = BB * TT;                          // 4096
    dim3 gg(D_MODEL / 64, M / 64);                  // (16, 64)
    gemm_bias_kernel<<<gg, 256, 0, stream>>>(x,  Wq, bq, Qw, M, D_MODEL, D_MODEL);
    gemm_bias_kernel<<<gg, 256, 0, stream>>>(x,  Wk, bk, Kw, M, D_MODEL, D_MODEL);
    gemm_bias_kernel<<<gg, 256, 0, stream>>>(x,  Wv, bv, Vw, M, D_MODEL, D_MODEL);

    const int nrows = BB * N_HEADS * TT;            // 65536
    attn_kernel<<<nrows / 8, 512, 0, stream>>>(Qw, Kw, Vw, Aw);

    gemm_bias_kernel<<<gg, 256, 0, stream>>>(Aw, Wo, bo, out, M, D_MODEL, D_MODEL);
}

// Round 2
// 295.261 us; speedup vs baseline: 9.6650x; 9.6650x over previous
//
#include <hip/hip_runtime.h>
#include <hip/hip_bf16.h>
#include <math.h>

#define D_MODEL 1024
#define N_HEADS 16
#define HD 64
#define BB 2
#define TT 2048
#define MROWS (BB*TT)   // 4096

typedef __attribute__((ext_vector_type(8))) short short8;
typedef __attribute__((ext_vector_type(4))) float f32x4;

static __device__ __forceinline__ void gload16(const void* g, void* l) {
    __builtin_amdgcn_global_load_lds(
        (const __attribute__((address_space(1))) void*)g,
        (__attribute__((address_space(3))) void*)l, 16, 0, 0);
}

static __device__ __forceinline__ unsigned short f2bf(float f) {
    union { float f; unsigned u; } x; x.f = f;
    unsigned r = (x.u + 0x7fffu + ((x.u >> 16) & 1u)) >> 16;
    return (unsigned short)r;
}

// ---------------------------------------------------------------------------
// Prep kernels
// ---------------------------------------------------------------------------
__global__ __launch_bounds__(256) void cast_x_kernel(
    const float* __restrict__ x, unsigned short* __restrict__ xb)
{
    int i = (blockIdx.x * 256 + threadIdx.x) * 8;
    float4 a = *(const float4*)(x + i);
    float4 b = *(const float4*)(x + i + 4);
    short8 o;
    o[0] = f2bf(a.x); o[1] = f2bf(a.y); o[2] = f2bf(a.z); o[3] = f2bf(a.w);
    o[4] = f2bf(b.x); o[5] = f2bf(b.y); o[6] = f2bf(b.z); o[7] = f2bf(b.w);
    *(short8*)(xb + i) = o;
}

// W [1024][1024] fp32 -> Wt [1024][1024] bf16 transposed: Wt[n][k] = W[k][n]
__global__ __launch_bounds__(256) void pack_w_kernel(
    const float* __restrict__ W, unsigned short* __restrict__ Wt)
{
    __shared__ float Ts[64][65];
    const int tid = threadIdx.x;
    const int n0 = blockIdx.x * 64, k0 = blockIdx.y * 64;
#pragma unroll
    for (int i = 0; i < 16; ++i) {
        int lin = i * 256 + tid;
        int kl = lin >> 6, nl = lin & 63;
        Ts[nl][kl] = W[(size_t)(k0 + kl) * 1024 + n0 + nl];
    }
    __syncthreads();
#pragma unroll
    for (int i = 0; i < 16; ++i) {
        int lin = i * 256 + tid;
        int nl = lin >> 6, kl = lin & 63;
        Wt[(size_t)(n0 + nl) * 1024 + k0 + kl] = f2bf(Ts[nl][kl]);
    }
}

__global__ void pack_bias_kernel(const float* __restrict__ bq,
                                 const float* __restrict__ bk,
                                 const float* __restrict__ bv,
                                 float* __restrict__ bqkv)
{
    int i = blockIdx.x * 256 + threadIdx.x;   // 0..3071
    float v = (i < 1024) ? bq[i] : ((i < 2048) ? bk[i - 1024] : bv[i - 2048]);
    bqkv[i] = v;
}

// V region of QKV [4096][3072] -> Vt [B][H][64][2048]: Vt[b][h][d][s]
__global__ __launch_bounds__(256) void vtrans_kernel(
    const unsigned short* __restrict__ QKV, unsigned short* __restrict__ Vt)
{
    __shared__ unsigned short Ts[64][65];
    const int tid = threadIdx.x;
    const int bx = blockIdx.x;
    const int st = bx & 31, h = (bx >> 5) & 15, b = bx >> 9;
    const int s0 = st * 64;
#pragma unroll
    for (int i = 0; i < 16; ++i) {
        int lin = i * 256 + tid;
        int sl = lin >> 6, dl = lin & 63;
        Ts[dl][sl] = QKV[(size_t)(b * TT + s0 + sl) * 3072 + 2048 + h * 64 + dl];
    }
    __syncthreads();
#pragma unroll
    for (int i = 0; i < 16; ++i) {
        int lin = i * 256 + tid;
        int dl = lin >> 6, sl = lin & 63;
        Vt[(size_t)((b * 16 + h) * 64 + dl) * TT + s0 + sl] = Ts[dl][sl];
    }
}

// ---------------------------------------------------------------------------
// MFMA GEMM: C[M][N] = A[M][K] @ Bt[N][K]^T + bias   (m97 structure)
// A,Bt bf16; C bf16 or fp32. 128x128 tile, BK=32, 256 threads (4 waves 2x2).
// ---------------------------------------------------------------------------
__global__ __launch_bounds__(256) void gemm_mfma_kernel(
    const unsigned short* __restrict__ A, const unsigned short* __restrict__ Bt,
    const float* __restrict__ bias, void* __restrict__ Cout,
    int N, int K, int bf16out)
{
    __shared__ __align__(16) unsigned short As[128 * 32];
    __shared__ __align__(16) unsigned short Bs[128 * 32];

    const int tid  = threadIdx.x;
    const int lane = tid & 63;
    const int ln   = lane & 15;
    const int qd   = lane >> 4;
    const int w    = tid >> 6;
    const int wm   = w >> 1, wn = w & 1;
    const int row0 = blockIdx.y * 128;
    const int col0 = blockIdx.x * 128;

    f32x4 acc[4][4];
#pragma unroll
    for (int mi = 0; mi < 4; ++mi)
#pragma unroll
        for (int ni = 0; ni < 4; ++ni)
            acc[mi][ni] = (f32x4){0.f, 0.f, 0.f, 0.f};

    // staging maps: slot s -> r = s>>2, c' = s&3, global chunk c = c' ^ ((r>>1)&3)
    const int s0 = tid, s1 = tid + 256;
    const int rA0 = s0 >> 2, cA0 = (s0 & 3) ^ ((rA0 >> 1) & 3);
    const int rA1 = s1 >> 2, cA1 = (s1 & 3) ^ ((rA1 >> 1) & 3);
    const unsigned short* Ag0 = A + (size_t)(row0 + rA0) * K + cA0 * 8;
    const unsigned short* Ag1 = A + (size_t)(row0 + rA1) * K + cA1 * 8;
    const unsigned short* Bg0 = Bt + (size_t)(col0 + rA0) * K + cA0 * 8;
    const unsigned short* Bg1 = Bt + (size_t)(col0 + rA1) * K + cA1 * 8;
    unsigned short* AsL0 = As + s0 * 8;
    unsigned short* AsL1 = As + s1 * 8;
    unsigned short* BsL0 = Bs + s0 * 8;
    unsigned short* BsL1 = Bs + s1 * 8;

    for (int kb = 0; kb < K; kb += 32) {
        if (kb) __syncthreads();
        gload16(Ag0 + kb, AsL0);
        gload16(Ag1 + kb, AsL1);
        gload16(Bg0 + kb, BsL0);
        gload16(Bg1 + kb, BsL1);
        __builtin_amdgcn_s_waitcnt(0);
        __syncthreads();

        short8 af[4], bf[4];
#pragma unroll
        for (int i = 0; i < 4; ++i) {
            int ra = wm * 64 + i * 16 + ln;
            int pa = ra * 4 + (qd ^ ((ra >> 1) & 3));
            af[i] = *(const short8*)(As + pa * 8);
            int rb = wn * 64 + i * 16 + ln;
            int pb = rb * 4 + (qd ^ ((rb >> 1) & 3));
            bf[i] = *(const short8*)(Bs + pb * 8);
        }
#pragma unroll
        for (int mi = 0; mi < 4; ++mi)
#pragma unroll
            for (int ni = 0; ni < 4; ++ni)
                acc[mi][ni] = __builtin_amdgcn_mfma_f32_16x16x32_bf16(
                    af[mi], bf[ni], acc[mi][ni], 0, 0, 0);
    }

    float bv[4];
#pragma unroll
    for (int ni = 0; ni < 4; ++ni)
        bv[ni] = bias[col0 + wn * 64 + ni * 16 + ln];

#pragma unroll
    for (int mi = 0; mi < 4; ++mi)
#pragma unroll
        for (int ni = 0; ni < 4; ++ni)
#pragma unroll
            for (int r = 0; r < 4; ++r) {
                float v = acc[mi][ni][r] + bv[ni];
                int row = row0 + wm * 64 + mi * 16 + qd * 4 + r;
                int col = col0 + wn * 64 + ni * 16 + ln;
                if (bf16out)
                    ((unsigned short*)Cout)[(size_t)row * N + col] = f2bf(v);
                else
                    ((float*)Cout)[(size_t)row * N + col] = v;
            }
}

// ---------------------------------------------------------------------------
// Flash attention, MFMA. Block = 256 thr (4 waves); one (b,h) 64-row Q tile.
// QKV [4096][3072] bf16 (Q|K|V), Vt [B][H][64][2048] bf16, Aout [4096][1024] bf16
// ---------------------------------------------------------------------------
__global__ __launch_bounds__(256) void attn_mfma_kernel(
    const unsigned short* __restrict__ QKV,
    const unsigned short* __restrict__ Vt,
    unsigned short* __restrict__ Aout)
{
    __shared__ __align__(16) unsigned short Ks[64 * 64];
    __shared__ __align__(16) unsigned short Vs[64 * 64];
    __shared__ __align__(16) float Ps[64 * 68];

    const int tid  = threadIdx.x;
    const int lane = tid & 63;
    const int ln   = lane & 15;
    const int qd   = lane >> 4;
    const int w    = tid >> 6;

    const int bx = blockIdx.x;
    const int qt = 31 - (bx & 31);          // heavy tiles dispatched first
    const int h  = (bx >> 5) & 15;
    const int b  = bx >> 9;

    const unsigned short* Qbase = QKV + (size_t)(b * TT + qt * 64) * 3072 + h * 64;
    const unsigned short* Kbase = QKV + (size_t)(b * TT) * 3072 + 1024 + h * 64;
    const unsigned short* Vbase = Vt + (size_t)((b * 16 + h) * 64) * TT;

    // ---- stage Q (64x64 bf16) into Ps area, hoist A-fragments into registers
    unsigned short* Qs = (unsigned short*)Ps;
    {
        const int t0 = tid, t1 = tid + 256;
        const int r0 = t0 >> 3, c0 = (t0 & 7) ^ (r0 & 7);
        const int r1 = t1 >> 3, c1 = (t1 & 7) ^ (r1 & 7);
        gload16(Qbase + (size_t)r0 * 3072 + c0 * 8, Qs + t0 * 8);
        gload16(Qbase + (size_t)r1 * 3072 + c1 * 8, Qs + t1 * 8);
        __builtin_amdgcn_s_waitcnt(0);
        __syncthreads();
    }
    short8 qa[2];
#pragma unroll
    for (int kk = 0; kk < 2; ++kk) {
        int r = w * 16 + ln;
        int ck = kk * 4 + qd;
        int pos = r * 8 + (ck ^ (r & 7));
        qa[kk] = *(const short8*)(Qs + pos * 8);
    }
    __syncthreads();   // all Q fragment reads done before Ps gets overwritten

    f32x4 o_acc[4];
#pragma unroll
    for (int dt = 0; dt < 4; ++dt) o_acc[dt] = (f32x4){0.f, 0.f, 0.f, 0.f};
    float m_i[4] = {-1e30f, -1e30f, -1e30f, -1e30f};
    float l_i[4] = {0.f, 0.f, 0.f, 0.f};

    for (int kc = 0; kc <= qt; ++kc) {
        __syncthreads();   // previous chunk's K/V consumers are done
        {
            const int t0 = tid, t1 = tid + 256;
            const int r0 = t0 >> 3, c0 = (t0 & 7) ^ (r0 & 7);
            const int r1 = t1 >> 3, c1 = (t1 & 7) ^ (r1 & 7);
            const unsigned short* Kc = Kbase + (size_t)kc * 64 * 3072;
            gload16(Kc + (size_t)r0 * 3072 + c0 * 8, Ks + t0 * 8);
            gload16(Kc + (size_t)r1 * 3072 + c1 * 8, Ks + t1 * 8);
            const unsigned short* Vc = Vbase + kc * 64;
            gload16(Vc + (size_t)r0 * TT + c0 * 8, Vs + t0 * 8);
            gload16(Vc + (size_t)r1 * TT + c1 * 8, Vs + t1 * 8);
            __builtin_amdgcn_s_waitcnt(0);
            __syncthreads();
        }

        // ---- S = Q K^T  (wave w: q rows 16w..16w+15, all 64 keys)
        f32x4 sx[4];
#pragma unroll
        for (int st = 0; st < 4; ++st) {
            sx[st] = (f32x4){0.f, 0.f, 0.f, 0.f};
#pragma unroll
            for (int kk = 0; kk < 2; ++kk) {
                int r = st * 16 + ln;
                int ck = kk * 4 + qd;
                int pos = r * 8 + (ck ^ (r & 7));
                short8 kf = *(const short8*)(Ks + pos * 8);
                sx[st] = __builtin_amdgcn_mfma_f32_16x16x32_bf16(qa[kk], kf, sx[st], 0, 0, 0);
            }
        }

        float sv[4][4];
#pragma unroll
        for (int st = 0; st < 4; ++st)
#pragma unroll
            for (int r = 0; r < 4; ++r)
                sv[st][r] = sx[st][r] * 0.125f;

        if (kc == qt) {   // diagonal chunk: causal mask
#pragma unroll
            for (int st = 0; st < 4; ++st)
#pragma unroll
                for (int r = 0; r < 4; ++r)
                    if (st * 16 + ln > w * 16 + qd * 4 + r) sv[st][r] = -1e30f;
        }

        // ---- online softmax (rows 4qd+r held across the 16 lanes of quad qd)
        float alpha[4], ps[4];
#pragma unroll
        for (int r = 0; r < 4; ++r) {
            float v = fmaxf(fmaxf(sv[0][r], sv[1][r]), fmaxf(sv[2][r], sv[3][r]));
            v = fmaxf(v, __shfl_xor(v, 1, 64));
            v = fmaxf(v, __shfl_xor(v, 2, 64));
            v = fmaxf(v, __shfl_xor(v, 4, 64));
            v = fmaxf(v, __shfl_xor(v, 8, 64));
            float mn = fmaxf(m_i[r], v);
            alpha[r] = __expf(m_i[r] - mn);
            m_i[r] = mn;
        }
#pragma unroll
        for (int st = 0; st < 4; ++st)
#pragma unroll
            for (int r = 0; r < 4; ++r)
                sv[st][r] = __expf(sv[st][r] - m_i[r]);
#pragma unroll
        for (int r = 0; r < 4; ++r) {
            float v = sv[0][r] + sv[1][r] + sv[2][r] + sv[3][r];
            v += __shfl_xor(v, 1, 64);
            v += __shfl_xor(v, 2, 64);
            v += __shfl_xor(v, 4, 64);
            v += __shfl_xor(v, 8, 64);
            ps[r] = v;
            l_i[r] = l_i[r] * alpha[r] + ps[r];
        }
#pragma unroll
        for (int dt = 0; dt < 4; ++dt)
#pragma unroll
            for (int r = 0; r < 4; ++r)
                o_acc[dt][r] *= alpha[r];

        // ---- P -> LDS (fp32, stride 68; wave-private rows -> no barrier)
#pragma unroll
        for (int st = 0; st < 4; ++st)
#pragma unroll
            for (int r = 0; r < 4; ++r)
                Ps[(w * 16 + qd * 4 + r) * 68 + st * 16 + ln] = sv[st][r];

        // ---- O += P @ V
#pragma unroll
        for (int kk = 0; kk < 2; ++kk) {
            const float* prow = Ps + (w * 16 + ln) * 68 + kk * 32 + qd * 8;
            float4 p0 = *(const float4*)(prow);
            float4 p1 = *(const float4*)(prow + 4);
            short8 pa;
            pa[0] = f2bf(p0.x); pa[1] = f2bf(p0.y); pa[2] = f2bf(p0.z); pa[3] = f2bf(p0.w);
            pa[4] = f2bf(p1.x); pa[5] = f2bf(p1.y); pa[6] = f2bf(p1.z); pa[7] = f2bf(p1.w);
#pragma unroll
            for (int dt = 0; dt < 4; ++dt) {
                int r = dt * 16 + ln;
                int ck = kk * 4 + qd;
                int pos = r * 8 + (ck ^ (r & 7));
                short8 vf = *(const short8*)(Vs + pos * 8);
                o_acc[dt] = __builtin_amdgcn_mfma_f32_16x16x32_bf16(pa, vf, o_acc[dt], 0, 0, 0);
            }
        }
    }

    // ---- epilogue: O /= l, store bf16
    float rl[4];
#pragma unroll
    for (int r = 0; r < 4; ++r) rl[r] = 1.0f / l_i[r];
#pragma unroll
    for (int dt = 0; dt < 4; ++dt)
#pragma unroll
        for (int r = 0; r < 4; ++r) {
            int row = b * TT + qt * 64 + w * 16 + qd * 4 + r;
            int col = h * 64 + dt * 16 + ln;
            Aout[(size_t)row * D_MODEL + col] = f2bf(o_acc[dt][r] * rl[r]);
        }
}

// ---------------------------------------------------------------------------
extern "C" void kernel_launch(void* const* d_in, const int* in_sizes, int n_in,
                              void* d_out, int out_size, void* d_ws, size_t ws_size,
                              hipStream_t stream) {
    const float* x  = (const float*)d_in[0];
    const float* Wq = (const float*)d_in[2];
    const float* bq = (const float*)d_in[3];
    const float* Wk = (const float*)d_in[4];
    const float* bk = (const float*)d_in[5];
    const float* Wv = (const float*)d_in[6];
    const float* bv = (const float*)d_in[7];
    const float* Wo = (const float*)d_in[8];
    const float* bo = (const float*)d_in[9];
    float* out = (float*)d_out;

    uint8_t* w8 = (uint8_t*)d_ws;
    const size_t MB = 1024 * 1024;
    unsigned short* xb    = (unsigned short*)(w8);                 // 8 MB [4096][1024]
    unsigned short* Wqkvt = (unsigned short*)(w8 + 8 * MB);        // 6 MB [3072][1024]
    unsigned short* Wot   = (unsigned short*)(w8 + 14 * MB);       // 2 MB [1024][1024]
    float*          bqkv  = (float*)(w8 + 16 * MB);                // 12 KB
    unsigned short* QKV   = (unsigned short*)(w8 + 17 * MB);       // 24 MB [4096][3072]
    unsigned short* Vt    = (unsigned short*)(w8 + 41 * MB);       // 8 MB [2][16][64][2048]
    unsigned short* Aout  = (unsigned short*)(w8 + 49 * MB);       // 8 MB [4096][1024]

    cast_x_kernel<<<MROWS * D_MODEL / (256 * 8), 256, 0, stream>>>(x, xb);
    pack_w_kernel<<<dim3(16, 16), 256, 0, stream>>>(Wq, Wqkvt);
    pack_w_kernel<<<dim3(16, 16), 256, 0, stream>>>(Wk, Wqkvt + 1024 * 1024);
    pack_w_kernel<<<dim3(16, 16), 256, 0, stream>>>(Wv, Wqkvt + 2 * 1024 * 1024);
    pack_w_kernel<<<dim3(16, 16), 256, 0, stream>>>(Wo, Wot);
    pack_bias_kernel<<<12, 256, 0, stream>>>(bq, bk, bv, bqkv);

    gemm_mfma_kernel<<<dim3(24, 32), 256, 0, stream>>>(xb, Wqkvt, bqkv, QKV, 3072, 1024, 1);
    vtrans_kernel<<<BB * N_HEADS * 32, 256, 0, stream>>>(QKV, Vt);
    attn_mfma_kernel<<<BB * N_HEADS * 32, 256, 0, stream>>>(QKV, Vt, Aout);
    gemm_mfma_kernel<<<dim3(8, 32), 256, 0, stream>>>(Aout, Wot, bo, out, 1024, 1024, 0);
}

// Round 3
// 215.211 us; speedup vs baseline: 13.2600x; 1.3720x over previous
//
#include <hip/hip_runtime.h>
#include <hip/hip_bf16.h>
#include <math.h>

#define D_MODEL 1024
#define N_HEADS 16
#define HD 64
#define BB 2
#define TT 2048
#define MROWS (BB*TT)   // 4096

typedef __attribute__((ext_vector_type(8))) short short8;
typedef __attribute__((ext_vector_type(4))) float f32x4;

static __device__ __forceinline__ void gload16(const void* g, void* l) {
    __builtin_amdgcn_global_load_lds(
        (const __attribute__((address_space(1))) void*)g,
        (__attribute__((address_space(3))) void*)l, 16, 0, 0);
}

static __device__ __forceinline__ unsigned short f2bf(float f) {
    union { float f; unsigned u; } x; x.f = f;
    unsigned r = (x.u + 0x7fffu + ((x.u >> 16) & 1u)) >> 16;
    return (unsigned short)r;
}

// pack two f32 -> bf16x2 (round-half-up) in one v_perm
static __device__ __forceinline__ unsigned pack_bf16x2(float lo, float hi) {
    union { float f; unsigned u; } a, b; a.f = lo; b.f = hi;
    return __builtin_amdgcn_perm(b.u + 0x8000u, a.u + 0x8000u, 0x07060302u);
}

// ---------------------------------------------------------------------------
// Prep kernels
// ---------------------------------------------------------------------------
__global__ __launch_bounds__(256) void cast_x_kernel(
    const float* __restrict__ x, unsigned short* __restrict__ xb)
{
    int i = (blockIdx.x * 256 + threadIdx.x) * 8;
    float4 a = *(const float4*)(x + i);
    float4 b = *(const float4*)(x + i + 4);
    short8 o;
    o[0] = f2bf(a.x); o[1] = f2bf(a.y); o[2] = f2bf(a.z); o[3] = f2bf(a.w);
    o[4] = f2bf(b.x); o[5] = f2bf(b.y); o[6] = f2bf(b.z); o[7] = f2bf(b.w);
    *(short8*)(xb + i) = o;
}

// all 4 weights [1024][1024] fp32 -> bf16 transposed, z picks the matrix
__global__ __launch_bounds__(256) void pack_w4_kernel(
    const float* __restrict__ Wq, const float* __restrict__ Wk,
    const float* __restrict__ Wv, const float* __restrict__ Wo,
    unsigned short* __restrict__ Wqkvt, unsigned short* __restrict__ Wot)
{
    __shared__ float Ts[64][65];
    const int z = blockIdx.z;
    const float* W = (z == 0) ? Wq : (z == 1) ? Wk : (z == 2) ? Wv : Wo;
    unsigned short* Wt = (z < 3) ? (Wqkvt + (size_t)z * 1024 * 1024) : Wot;
    const int tid = threadIdx.x;
    const int n0 = blockIdx.x * 64, k0 = blockIdx.y * 64;
#pragma unroll
    for (int i = 0; i < 16; ++i) {
        int lin = i * 256 + tid;
        int kl = lin >> 6, nl = lin & 63;
        Ts[nl][kl] = W[(size_t)(k0 + kl) * 1024 + n0 + nl];
    }
    __syncthreads();
#pragma unroll
    for (int i = 0; i < 16; ++i) {
        int lin = i * 256 + tid;
        int nl = lin >> 6, kl = lin & 63;
        Wt[(size_t)(n0 + nl) * 1024 + k0 + kl] = f2bf(Ts[nl][kl]);
    }
}

__global__ void pack_bias_kernel(const float* __restrict__ bq,
                                 const float* __restrict__ bk,
                                 const float* __restrict__ bv,
                                 float* __restrict__ bqkv)
{
    int i = blockIdx.x * 256 + threadIdx.x;   // 0..3071
    float v = (i < 1024) ? bq[i] : ((i < 2048) ? bk[i - 1024] : bv[i - 2048]);
    bqkv[i] = v;
}

// V region of QKV [4096][3072] -> Vt [B][H][64][2048]: Vt[b][h][d][s]
__global__ __launch_bounds__(256) void vtrans_kernel(
    const unsigned short* __restrict__ QKV, unsigned short* __restrict__ Vt)
{
    __shared__ unsigned short Ts[64][65];
    const int tid = threadIdx.x;
    const int bx = blockIdx.x;
    const int st = bx & 31, h = (bx >> 5) & 15, b = bx >> 9;
    const int s0 = st * 64;
#pragma unroll
    for (int i = 0; i < 16; ++i) {
        int lin = i * 256 + tid;
        int sl = lin >> 6, dl = lin & 63;
        Ts[dl][sl] = QKV[(size_t)(b * TT + s0 + sl) * 3072 + 2048 + h * 64 + dl];
    }
    __syncthreads();
#pragma unroll
    for (int i = 0; i < 16; ++i) {
        int lin = i * 256 + tid;
        int dl = lin >> 6, sl = lin & 63;
        Vt[(size_t)((b * 16 + h) * 64 + dl) * TT + s0 + sl] = Ts[dl][sl];
    }
}

// ---------------------------------------------------------------------------
// MFMA GEMM: C[M][N] = A[M][K] @ Bt[N][K]^T + bias   (m97 structure)
// cols < qcols additionally scaled by 0.125 after bias (softmax scale fold)
// ---------------------------------------------------------------------------
__global__ __launch_bounds__(256) void gemm_mfma_kernel(
    const unsigned short* __restrict__ A, const unsigned short* __restrict__ Bt,
    const float* __restrict__ bias, void* __restrict__ Cout,
    int N, int K, int bf16out, int qcols)
{
    __shared__ __align__(16) unsigned short As[128 * 32];
    __shared__ __align__(16) unsigned short Bs[128 * 32];

    const int tid  = threadIdx.x;
    const int lane = tid & 63;
    const int ln   = lane & 15;
    const int qd   = lane >> 4;
    const int w    = tid >> 6;
    const int wm   = w >> 1, wn = w & 1;
    const int row0 = blockIdx.y * 128;
    const int col0 = blockIdx.x * 128;

    f32x4 acc[4][4];
#pragma unroll
    for (int mi = 0; mi < 4; ++mi)
#pragma unroll
        for (int ni = 0; ni < 4; ++ni)
            acc[mi][ni] = (f32x4){0.f, 0.f, 0.f, 0.f};

    const int s0 = tid, s1 = tid + 256;
    const int rA0 = s0 >> 2, cA0 = (s0 & 3) ^ ((rA0 >> 1) & 3);
    const int rA1 = s1 >> 2, cA1 = (s1 & 3) ^ ((rA1 >> 1) & 3);
    const unsigned short* Ag0 = A + (size_t)(row0 + rA0) * K + cA0 * 8;
    const unsigned short* Ag1 = A + (size_t)(row0 + rA1) * K + cA1 * 8;
    const unsigned short* Bg0 = Bt + (size_t)(col0 + rA0) * K + cA0 * 8;
    const unsigned short* Bg1 = Bt + (size_t)(col0 + rA1) * K + cA1 * 8;
    unsigned short* AsL0 = As + s0 * 8;
    unsigned short* AsL1 = As + s1 * 8;
    unsigned short* BsL0 = Bs + s0 * 8;
    unsigned short* BsL1 = Bs + s1 * 8;

    for (int kb = 0; kb < K; kb += 32) {
        if (kb) __syncthreads();
        gload16(Ag0 + kb, AsL0);
        gload16(Ag1 + kb, AsL1);
        gload16(Bg0 + kb, BsL0);
        gload16(Bg1 + kb, BsL1);
        __builtin_amdgcn_s_waitcnt(0);
        __syncthreads();

        short8 af[4], bf[4];
#pragma unroll
        for (int i = 0; i < 4; ++i) {
            int ra = wm * 64 + i * 16 + ln;
            int pa = ra * 4 + (qd ^ ((ra >> 1) & 3));
            af[i] = *(const short8*)(As + pa * 8);
            int rb = wn * 64 + i * 16 + ln;
            int pb = rb * 4 + (qd ^ ((rb >> 1) & 3));
            bf[i] = *(const short8*)(Bs + pb * 8);
        }
#pragma unroll
        for (int mi = 0; mi < 4; ++mi)
#pragma unroll
            for (int ni = 0; ni < 4; ++ni)
                acc[mi][ni] = __builtin_amdgcn_mfma_f32_16x16x32_bf16(
                    af[mi], bf[ni], acc[mi][ni], 0, 0, 0);
    }

    float bv[4], scl[4];
#pragma unroll
    for (int ni = 0; ni < 4; ++ni) {
        bv[ni]  = bias[col0 + wn * 64 + ni * 16 + ln];
        scl[ni] = (col0 + wn * 64 + ni * 16 < qcols) ? 0.125f : 1.0f;
    }

#pragma unroll
    for (int mi = 0; mi < 4; ++mi)
#pragma unroll
        for (int ni = 0; ni < 4; ++ni)
#pragma unroll
            for (int r = 0; r < 4; ++r) {
                float v = (acc[mi][ni][r] + bv[ni]) * scl[ni];
                int row = row0 + wm * 64 + mi * 16 + qd * 4 + r;
                int col = col0 + wn * 64 + ni * 16 + ln;
                if (bf16out)
                    ((unsigned short*)Cout)[(size_t)row * N + col] = f2bf(v);
                else
                    ((float*)Cout)[(size_t)row * N + col] = v;
            }
}

// ---------------------------------------------------------------------------
// Flash attention v3: wave-independent key chunks, zero barriers in K-loop.
// Block = 256 thr (4 waves) handles q-tile pair {31-p, p} of one (b,h).
// Each wave w: chunks kc = w, w+4, ... with private (m,l,O^T) over all 64 q.
// S^T = mfma(K,Q); P^T packed bf16 via wave-private LDS; O^T = V^T P^T.
// Merge across waves via LDS at tile end.
// ---------------------------------------------------------------------------
#define PSTRIDE 136                 // bytes per q-row of P (64 keys bf16 + 8B pad)
#define LDS_TOTAL (4*64*PSTRIDE + 2048)   // 34816 P-union-Oacc + 2048 ml

__global__ __launch_bounds__(256, 2) void attn_mfma_kernel(
    const unsigned short* __restrict__ QKV,
    const unsigned short* __restrict__ Vt,
    unsigned short* __restrict__ Aout)
{
    __shared__ __align__(16) unsigned char lds[LDS_TOTAL];

    const int tid  = threadIdx.x;
    const int lane = tid & 63;
    const int ln   = lane & 15;
    const int qd   = lane >> 4;
    const int qd4  = qd * 4;
    const int w    = tid >> 6;

    const int bx = blockIdx.x;
    const int p  = bx & 15;
    const int h  = (bx >> 4) & 15;
    const int b  = bx >> 8;

    unsigned char* Pb   = lds + w * (64 * PSTRIDE);   // wave-private P buffer
    float*         Oacc = (float*)lds;                // aliases P (live post-loop)
    float*         mlm  = (float*)(lds + 4 * 64 * PSTRIDE);
    float*         mll  = mlm + 256;

    const unsigned short* Kh = QKV + 1024 + h * 64;
    const unsigned short* Qh = QKV + h * 64;
    const unsigned short* Vh = Vt + (size_t)((b * 16 + h) * 64) * TT;

    for (int ti = 0; ti < 2; ++ti) {
        const int qt = ti ? p : (31 - p);
        __syncthreads();   // P/Oacc region safe to reuse

        // ---- Q fragments (B-operand): q = qt*64 + q4*16 + ln, k = kk*32+qd*8+j
        short8 qa[4][2];
        {
            const unsigned short* Qb = Qh + (size_t)(b * TT + qt * 64) * 3072;
#pragma unroll
            for (int q4 = 0; q4 < 4; ++q4)
#pragma unroll
                for (int kk = 0; kk < 2; ++kk)
                    qa[q4][kk] = *(const short8*)(Qb + (size_t)(q4 * 16 + ln) * 3072 + kk * 32 + qd * 8);
        }

        f32x4 O[4][4];     // [dt][q4]: O^T tile, row d = dt*16+qd*4+r, col q = q4*16+ln
#pragma unroll
        for (int dt = 0; dt < 4; ++dt)
#pragma unroll
            for (int q4 = 0; q4 < 4; ++q4)
                O[dt][q4] = (f32x4){0.f, 0.f, 0.f, 0.f};
        float m_i[4] = {-1e30f, -1e30f, -1e30f, -1e30f};
        float l_i[4] = {0.f, 0.f, 0.f, 0.f};

        for (int kc = w; kc <= qt; kc += 4) {
            const unsigned short* Kc = Kh + (size_t)(b * TT + kc * 64) * 3072;
            const unsigned short* Vc = Vh + kc * 64;

            short8 kf[4][2], vf[4][2];
#pragma unroll
            for (int kt = 0; kt < 4; ++kt)
#pragma unroll
                for (int kk = 0; kk < 2; ++kk)
                    kf[kt][kk] = *(const short8*)(Kc + (size_t)(kt * 16 + ln) * 3072 + kk * 32 + qd * 8);
#pragma unroll
            for (int dt = 0; dt < 4; ++dt)
#pragma unroll
                for (int kk = 0; kk < 2; ++kk)
                    vf[dt][kk] = *(const short8*)(Vc + (size_t)(dt * 16 + ln) * TT + kk * 32 + qd * 8);

            // ---- S^T tiles: row = key kt*16+qd*4+r, col = q q4*16+ln
            f32x4 st[4][4];
#pragma unroll
            for (int kt = 0; kt < 4; ++kt)
#pragma unroll
                for (int q4 = 0; q4 < 4; ++q4) {
                    f32x4 a = (f32x4){0.f, 0.f, 0.f, 0.f};
                    a = __builtin_amdgcn_mfma_f32_16x16x32_bf16(kf[kt][0], qa[q4][0], a, 0, 0, 0);
                    a = __builtin_amdgcn_mfma_f32_16x16x32_bf16(kf[kt][1], qa[q4][1], a, 0, 0, 0);
                    st[kt][q4] = a;
                }

            if (kc == qt) {   // diagonal chunk: mask key>q
#pragma unroll
                for (int kt = 0; kt < 4; ++kt)
#pragma unroll
                    for (int q4 = 0; q4 < 4; ++q4)
#pragma unroll
                        for (int r = 0; r < 4; ++r)
                            if (kt * 16 + qd4 + r > q4 * 16 + ln)
                                st[kt][q4][r] = -1e30f;
            }

            // ---- online softmax per q-column
            float alpha[4];
#pragma unroll
            for (int q4 = 0; q4 < 4; ++q4) {
                float mx = st[0][q4][0];
#pragma unroll
                for (int kt = 0; kt < 4; ++kt)
#pragma unroll
                    for (int r = 0; r < 4; ++r)
                        mx = fmaxf(mx, st[kt][q4][r]);
                mx = fmaxf(mx, __shfl_xor(mx, 16, 64));
                mx = fmaxf(mx, __shfl_xor(mx, 32, 64));
                float mn = fmaxf(m_i[q4], mx);
                alpha[q4] = __expf(m_i[q4] - mn);
                m_i[q4] = mn;
            }
#pragma unroll
            for (int kt = 0; kt < 4; ++kt)
#pragma unroll
                for (int q4 = 0; q4 < 4; ++q4)
#pragma unroll
                    for (int r = 0; r < 4; ++r)
                        st[kt][q4][r] = __expf(st[kt][q4][r] - m_i[q4]);
#pragma unroll
            for (int q4 = 0; q4 < 4; ++q4) {
                float sm = 0.f;
#pragma unroll
                for (int kt = 0; kt < 4; ++kt)
#pragma unroll
                    for (int r = 0; r < 4; ++r)
                        sm += st[kt][q4][r];
                sm += __shfl_xor(sm, 16, 64);
                sm += __shfl_xor(sm, 32, 64);
                l_i[q4] = l_i[q4] * alpha[q4] + sm;
            }
#pragma unroll
            for (int dt = 0; dt < 4; ++dt)
#pragma unroll
                for (int q4 = 0; q4 < 4; ++q4) {
                    O[dt][q4][0] *= alpha[q4]; O[dt][q4][1] *= alpha[q4];
                    O[dt][q4][2] *= alpha[q4]; O[dt][q4][3] *= alpha[q4];
                }

            // ---- P^T -> wave-private LDS as P[q][key] bf16
#pragma unroll
            for (int kt = 0; kt < 4; ++kt)
#pragma unroll
                for (int q4 = 0; q4 < 4; ++q4) {
                    unsigned u0 = pack_bf16x2(st[kt][q4][0], st[kt][q4][1]);
                    unsigned u1 = pack_bf16x2(st[kt][q4][2], st[kt][q4][3]);
                    *(uint2*)(Pb + (q4 * 16 + ln) * PSTRIDE + kt * 32 + qd * 8) =
                        make_uint2(u0, u1);
                }

            // ---- O^T += V^T P^T
#pragma unroll
            for (int kk = 0; kk < 2; ++kk)
#pragma unroll
                for (int q4 = 0; q4 < 4; ++q4) {
                    union { struct { uint2 a, b; } u; short8 s; } y;
                    const unsigned char* yp = Pb + (q4 * 16 + ln) * PSTRIDE + kk * 64 + qd * 16;
                    y.u.a = *(const uint2*)(yp);
                    y.u.b = *(const uint2*)(yp + 8);
#pragma unroll
                    for (int dt = 0; dt < 4; ++dt)
                        O[dt][q4] = __builtin_amdgcn_mfma_f32_16x16x32_bf16(
                            vf[dt][kk], y.s, O[dt][q4], 0, 0, 0);
                }
        }

        // ---- cross-wave merge
        if (qd == 0) {
#pragma unroll
            for (int q4 = 0; q4 < 4; ++q4) {
                mlm[w * 64 + q4 * 16 + ln] = m_i[q4];
                mll[w * 64 + q4 * 16 + ln] = l_i[q4];
            }
        }
        __syncthreads();

        float fac[4];
#pragma unroll
        for (int q4 = 0; q4 < 4; ++q4) {
            int q = q4 * 16 + ln;
            float m0 = mlm[q], m1 = mlm[64 + q], m2 = mlm[128 + q], m3 = mlm[192 + q];
            float M = fmaxf(fmaxf(m0, m1), fmaxf(m2, m3));
            float f0 = __expf(m0 - M), f1 = __expf(m1 - M);
            float f2 = __expf(m2 - M), f3 = __expf(m3 - M);
            float L = f0 * mll[q] + f1 * mll[64 + q] + f2 * mll[128 + q] + f3 * mll[192 + q];
            float myf = (w == 0) ? f0 : (w == 1) ? f1 : (w == 2) ? f2 : f3;
            fac[q4] = myf / L;
        }
#pragma unroll
        for (int dt = 0; dt < 4; ++dt)
#pragma unroll
            for (int q4 = 0; q4 < 4; ++q4) {
                O[dt][q4][0] *= fac[q4]; O[dt][q4][1] *= fac[q4];
                O[dt][q4][2] *= fac[q4]; O[dt][q4][3] *= fac[q4];
            }

        // Oacc[q][d], stride 68 f32: wave turns to avoid races
        for (int wv = 0; wv < 4; ++wv) {
            if (w == wv) {
#pragma unroll
                for (int dt = 0; dt < 4; ++dt)
#pragma unroll
                    for (int q4 = 0; q4 < 4; ++q4) {
                        float* pp = Oacc + (q4 * 16 + ln) * 68 + dt * 16 + qd4;
                        if (wv == 0) {
                            *(f32x4*)pp = O[dt][q4];
                        } else {
                            f32x4 t = *(const f32x4*)pp;
                            t += O[dt][q4];
                            *(f32x4*)pp = t;
                        }
                    }
            }
            __syncthreads();
        }

        // ---- epilogue: 256 threads write 64q x 64d bf16
        {
            int q = tid >> 2, dg = tid & 3;
            const float* rowp = Oacc + q * 68 + dg * 16;
            short8 s0v, s1v;
#pragma unroll
            for (int i = 0; i < 8; ++i) {
                s0v[i] = f2bf(rowp[i]);
                s1v[i] = f2bf(rowp[8 + i]);
            }
            size_t orow = (size_t)(b * TT + qt * 64 + q) * D_MODEL + h * 64 + dg * 16;
            *(short8*)(Aout + orow) = s0v;
            *(short8*)(Aout + orow + 8) = s1v;
        }
    }
}

// ---------------------------------------------------------------------------
extern "C" void kernel_launch(void* const* d_in, const int* in_sizes, int n_in,
                              void* d_out, int out_size, void* d_ws, size_t ws_size,
                              hipStream_t stream) {
    const float* x  = (const float*)d_in[0];
    const float* Wq = (const float*)d_in[2];
    const float* bq = (const float*)d_in[3];
    const float* Wk = (const float*)d_in[4];
    const float* bk = (const float*)d_in[5];
    const float* Wv = (const float*)d_in[6];
    const float* bv = (const float*)d_in[7];
    const float* Wo = (const float*)d_in[8];
    const float* bo = (const float*)d_in[9];
    float* out = (float*)d_out;

    uint8_t* w8 = (uint8_t*)d_ws;
    const size_t MB = 1024 * 1024;
    unsigned short* xb    = (unsigned short*)(w8);                 // 8 MB [4096][1024]
    unsigned short* Wqkvt = (unsigned short*)(w8 + 8 * MB);        // 6 MB [3072][1024]
    unsigned short* Wot   = (unsigned short*)(w8 + 14 * MB);       // 2 MB [1024][1024]
    float*          bqkv  = (float*)(w8 + 16 * MB);                // 12 KB
    unsigned short* QKV   = (unsigned short*)(w8 + 17 * MB);       // 24 MB [4096][3072]
    unsigned short* Vt    = (unsigned short*)(w8 + 41 * MB);       // 8 MB [2][16][64][2048]
    unsigned short* Aout  = (unsigned short*)(w8 + 49 * MB);       // 8 MB [4096][1024]

    cast_x_kernel<<<MROWS * D_MODEL / (256 * 8), 256, 0, stream>>>(x, xb);
    pack_w4_kernel<<<dim3(16, 16, 4), 256, 0, stream>>>(Wq, Wk, Wv, Wo, Wqkvt, Wot);
    pack_bias_kernel<<<12, 256, 0, stream>>>(bq, bk, bv, bqkv);

    gemm_mfma_kernel<<<dim3(24, 32), 256, 0, stream>>>(xb, Wqkvt, bqkv, QKV, 3072, 1024, 1, 1024);
    vtrans_kernel<<<BB * N_HEADS * 32, 256, 0, stream>>>(QKV, Vt);
    attn_mfma_kernel<<<BB * N_HEADS * 16, 256, 0, stream>>>(QKV, Vt, Aout);
    gemm_mfma_kernel<<<dim3(8, 32), 256, 0, stream>>>(Aout, Wot, bo, out, 1024, 1024, 0, 0);
}

// Round 4
// 197.842 us; speedup vs baseline: 14.4241x; 1.0878x over previous
//
#include <hip/hip_runtime.h>
#include <hip/hip_bf16.h>
#include <math.h>

#define D_MODEL 1024
#define N_HEADS 16
#define HD 64
#define BB 2
#define TT 2048
#define MROWS (BB*TT)   // 4096

typedef __attribute__((ext_vector_type(8))) short short8;
typedef __attribute__((ext_vector_type(4))) float f32x4;

static __device__ __forceinline__ void gload16(const void* g, void* l) {
    __builtin_amdgcn_global_load_lds(
        (const __attribute__((address_space(1))) void*)g,
        (__attribute__((address_space(3))) void*)l, 16, 0, 0);
}

static __device__ __forceinline__ unsigned short f2bf(float f) {
    union { float f; unsigned u; } x; x.f = f;
    unsigned r = (x.u + 0x7fffu + ((x.u >> 16) & 1u)) >> 16;
    return (unsigned short)r;
}

// pack two f32 -> bf16x2 (round-half-up) in one v_perm
static __device__ __forceinline__ unsigned pack_bf16x2(float lo, float hi) {
    union { float f; unsigned u; } a, b; a.f = lo; b.f = hi;
    return __builtin_amdgcn_perm(b.u + 0x8000u, a.u + 0x8000u, 0x07060302u);
}

// ---------------------------------------------------------------------------
// Fused prep: blocks [0,1024) pack 4 weights (bf16, transposed);
// [1024,3072) cast x to bf16; block 3072 packs the qkv bias.
// ---------------------------------------------------------------------------
__global__ __launch_bounds__(256) void prep_kernel(
    const float* __restrict__ x,
    const float* __restrict__ Wq, const float* __restrict__ Wk,
    const float* __restrict__ Wv, const float* __restrict__ Wo,
    const float* __restrict__ bq, const float* __restrict__ bk,
    const float* __restrict__ bv,
    unsigned short* __restrict__ xb, unsigned short* __restrict__ Wqkvt,
    unsigned short* __restrict__ Wot, float* __restrict__ bqkv)
{
    __shared__ float Ts[64][65];
    const int bx = blockIdx.x, tid = threadIdx.x;
    if (bx < 1024) {
        const int z = bx >> 8, rem = bx & 255;
        const float* W = (z == 0) ? Wq : (z == 1) ? Wk : (z == 2) ? Wv : Wo;
        unsigned short* Wt = (z < 3) ? (Wqkvt + (size_t)z * 1024 * 1024) : Wot;
        const int n0 = (rem & 15) * 64, k0 = (rem >> 4) * 64;
#pragma unroll
        for (int i = 0; i < 16; ++i) {
            int lin = i * 256 + tid;
            int kl = lin >> 6, nl = lin & 63;
            Ts[nl][kl] = W[(size_t)(k0 + kl) * 1024 + n0 + nl];
        }
        __syncthreads();
#pragma unroll
        for (int i = 0; i < 16; ++i) {
            int lin = i * 256 + tid;
            int nl = lin >> 6, kl = lin & 63;
            Wt[(size_t)(n0 + nl) * 1024 + k0 + kl] = f2bf(Ts[nl][kl]);
        }
    } else if (bx < 3072) {
        int i = ((bx - 1024) * 256 + tid) * 8;
        float4 a = *(const float4*)(x + i);
        float4 b = *(const float4*)(x + i + 4);
        short8 o;
        o[0] = f2bf(a.x); o[1] = f2bf(a.y); o[2] = f2bf(a.z); o[3] = f2bf(a.w);
        o[4] = f2bf(b.x); o[5] = f2bf(b.y); o[6] = f2bf(b.z); o[7] = f2bf(b.w);
        *(short8*)(xb + i) = o;
    } else {
#pragma unroll
        for (int j = 0; j < 12; ++j) {
            int i = j * 256 + tid;
            float v = (i < 1024) ? bq[i] : ((i < 2048) ? bk[i - 1024] : bv[i - 2048]);
            bqkv[i] = v;
        }
    }
}

// ---------------------------------------------------------------------------
// MFMA GEMM (QKV): C[M][N] = A @ Bt^T + bias. 128x128 tile, BK=32, 4 waves.
// cols < qcols scaled by 0.125 (softmax fold). Block-cols >= 2048 are the V
// projection: written transposed to Vt[b][h][d][t] instead of C.
// XCD-rectangle swizzle: each XCD gets a 12x8 tile rectangle.
// ---------------------------------------------------------------------------
__global__ __launch_bounds__(256) void gemm_mfma_kernel(
    const unsigned short* __restrict__ A, const unsigned short* __restrict__ Bt,
    const float* __restrict__ bias, unsigned short* __restrict__ Cout,
    unsigned short* __restrict__ Vt, int N, int K, int qcols)
{
    __shared__ __align__(16) unsigned short As[128 * 32];
    __shared__ __align__(16) unsigned short Bs[128 * 32];

    const int tid  = threadIdx.x;
    const int lane = tid & 63;
    const int ln   = lane & 15;
    const int qd   = lane >> 4;
    const int w    = tid >> 6;
    const int wm   = w >> 1, wn = w & 1;

    // XCD swizzle (heuristic: linear block id round-robins XCDs)
    const int lin  = blockIdx.y * gridDim.x + blockIdx.x;
    const int xcd  = lin & 7;
    const int slot = lin >> 3;
    const int sxw  = gridDim.x >> 1;
    const int syw  = ((gridDim.x * gridDim.y) >> 3) / sxw;
    const int sx   = slot % sxw, sy = slot / sxw;
    const int row0 = ((xcd >> 1) * syw + sy) * 128;
    const int col0 = ((xcd & 1) * sxw + sx) * 128;

    f32x4 acc[4][4];
#pragma unroll
    for (int mi = 0; mi < 4; ++mi)
#pragma unroll
        for (int ni = 0; ni < 4; ++ni)
            acc[mi][ni] = (f32x4){0.f, 0.f, 0.f, 0.f};

    const int s0 = tid, s1 = tid + 256;
    const int rA0 = s0 >> 2, cA0 = (s0 & 3) ^ ((rA0 >> 1) & 3);
    const int rA1 = s1 >> 2, cA1 = (s1 & 3) ^ ((rA1 >> 1) & 3);
    const unsigned short* Ag0 = A + (size_t)(row0 + rA0) * K + cA0 * 8;
    const unsigned short* Ag1 = A + (size_t)(row0 + rA1) * K + cA1 * 8;
    const unsigned short* Bg0 = Bt + (size_t)(col0 + rA0) * K + cA0 * 8;
    const unsigned short* Bg1 = Bt + (size_t)(col0 + rA1) * K + cA1 * 8;
    unsigned short* AsL0 = As + s0 * 8;
    unsigned short* AsL1 = As + s1 * 8;
    unsigned short* BsL0 = Bs + s0 * 8;
    unsigned short* BsL1 = Bs + s1 * 8;

    for (int kb = 0; kb < K; kb += 32) {
        if (kb) __syncthreads();
        gload16(Ag0 + kb, AsL0);
        gload16(Ag1 + kb, AsL1);
        gload16(Bg0 + kb, BsL0);
        gload16(Bg1 + kb, BsL1);
        __builtin_amdgcn_s_waitcnt(0);
        __syncthreads();

        short8 af[4], bf[4];
#pragma unroll
        for (int i = 0; i < 4; ++i) {
            int ra = wm * 64 + i * 16 + ln;
            int pa = ra * 4 + (qd ^ ((ra >> 1) & 3));
            af[i] = *(const short8*)(As + pa * 8);
            int rb = wn * 64 + i * 16 + ln;
            int pb = rb * 4 + (qd ^ ((rb >> 1) & 3));
            bf[i] = *(const short8*)(Bs + pb * 8);
        }
#pragma unroll
        for (int mi = 0; mi < 4; ++mi)
#pragma unroll
            for (int ni = 0; ni < 4; ++ni)
                acc[mi][ni] = __builtin_amdgcn_mfma_f32_16x16x32_bf16(
                    af[mi], bf[ni], acc[mi][ni], 0, 0, 0);
    }

    float bv[4];
#pragma unroll
    for (int ni = 0; ni < 4; ++ni)
        bv[ni] = bias[col0 + wn * 64 + ni * 16 + ln];

    if (col0 >= 2048) {
        // ---- V projection: write transposed into Vt[b][h][d][t]
        const int h = ((col0 - 2048) >> 6) + wn;
#pragma unroll
        for (int mi = 0; mi < 4; ++mi) {
            int row = row0 + wm * 64 + mi * 16 + qd * 4;
            int b = row >> 11, t = row & 2047;
#pragma unroll
            for (int ni = 0; ni < 4; ++ni) {
                int d = ni * 16 + ln;
                float v0 = acc[mi][ni][0] + bv[ni];
                float v1 = acc[mi][ni][1] + bv[ni];
                float v2 = acc[mi][ni][2] + bv[ni];
                float v3 = acc[mi][ni][3] + bv[ni];
                unsigned u0 = pack_bf16x2(v0, v1);
                unsigned u1 = pack_bf16x2(v2, v3);
                *(uint2*)(Vt + (size_t)((b * 16 + h) * 64 + d) * TT + t) =
                    make_uint2(u0, u1);
            }
        }
    } else {
        float scl[4];
#pragma unroll
        for (int ni = 0; ni < 4; ++ni)
            scl[ni] = (col0 + wn * 64 + ni * 16 < qcols) ? 0.125f : 1.0f;
#pragma unroll
        for (int mi = 0; mi < 4; ++mi)
#pragma unroll
            for (int ni = 0; ni < 4; ++ni)
#pragma unroll
                for (int r = 0; r < 4; ++r) {
                    float v = (acc[mi][ni][r] + bv[ni]) * scl[ni];
                    int row = row0 + wm * 64 + mi * 16 + qd * 4 + r;
                    int col = col0 + wn * 64 + ni * 16 + ln;
                    Cout[(size_t)row * N + col] = f2bf(v);
                }
    }
}

// ---------------------------------------------------------------------------
// MFMA GEMM (output proj): 128x64 tile -> 512 blocks (2/CU). fp32 out.
// ---------------------------------------------------------------------------
__global__ __launch_bounds__(256) void gemm_mfma_n64_kernel(
    const unsigned short* __restrict__ A, const unsigned short* __restrict__ Bt,
    const float* __restrict__ bias, float* __restrict__ Cout, int N, int K)
{
    __shared__ __align__(16) unsigned short As[128 * 32];
    __shared__ __align__(16) unsigned short Bs[64 * 32];

    const int tid  = threadIdx.x;
    const int lane = tid & 63;
    const int ln   = lane & 15;
    const int qd   = lane >> 4;
    const int w    = tid >> 6;

    const int lin  = blockIdx.y * gridDim.x + blockIdx.x;
    const int xcd  = lin & 7;
    const int slot = lin >> 3;
    const int sxw  = gridDim.x >> 1;
    const int syw  = ((gridDim.x * gridDim.y) >> 3) / sxw;
    const int sx   = slot % sxw, sy = slot / sxw;
    const int row0 = ((xcd >> 1) * syw + sy) * 128;
    const int col0 = ((xcd & 1) * sxw + sx) * 64;

    f32x4 acc[2][4];
#pragma unroll
    for (int mi = 0; mi < 2; ++mi)
#pragma unroll
        for (int ni = 0; ni < 4; ++ni)
            acc[mi][ni] = (f32x4){0.f, 0.f, 0.f, 0.f};

    const int s0 = tid, s1 = tid + 256;
    const int rA0 = s0 >> 2, cA0 = (s0 & 3) ^ ((rA0 >> 1) & 3);
    const int rA1 = s1 >> 2, cA1 = (s1 & 3) ^ ((rA1 >> 1) & 3);
    const unsigned short* Ag0 = A + (size_t)(row0 + rA0) * K + cA0 * 8;
    const unsigned short* Ag1 = A + (size_t)(row0 + rA1) * K + cA1 * 8;
    const unsigned short* Bg0 = Bt + (size_t)(col0 + rA0) * K + cA0 * 8;
    unsigned short* AsL0 = As + s0 * 8;
    unsigned short* AsL1 = As + s1 * 8;
    unsigned short* BsL0 = Bs + s0 * 8;

    for (int kb = 0; kb < K; kb += 32) {
        if (kb) __syncthreads();
        gload16(Ag0 + kb, AsL0);
        gload16(Ag1 + kb, AsL1);
        gload16(Bg0 + kb, BsL0);
        __builtin_amdgcn_s_waitcnt(0);
        __syncthreads();

        short8 af[2], bf[4];
#pragma unroll
        for (int i = 0; i < 2; ++i) {
            int ra = w * 32 + i * 16 + ln;
            int pa = ra * 4 + (qd ^ ((ra >> 1) & 3));
            af[i] = *(const short8*)(As + pa * 8);
        }
#pragma unroll
        for (int i = 0; i < 4; ++i) {
            int rb = i * 16 + ln;
            int pb = rb * 4 + (qd ^ ((rb >> 1) & 3));
            bf[i] = *(const short8*)(Bs + pb * 8);
        }
#pragma unroll
        for (int mi = 0; mi < 2; ++mi)
#pragma unroll
            for (int ni = 0; ni < 4; ++ni)
                acc[mi][ni] = __builtin_amdgcn_mfma_f32_16x16x32_bf16(
                    af[mi], bf[ni], acc[mi][ni], 0, 0, 0);
    }

    float bv[4];
#pragma unroll
    for (int ni = 0; ni < 4; ++ni)
        bv[ni] = bias[col0 + ni * 16 + ln];

#pragma unroll
    for (int mi = 0; mi < 2; ++mi)
#pragma unroll
        for (int ni = 0; ni < 4; ++ni)
#pragma unroll
            for (int r = 0; r < 4; ++r) {
                int row = row0 + w * 32 + mi * 16 + qd * 4 + r;
                int col = col0 + ni * 16 + ln;
                Cout[(size_t)row * N + col] = acc[mi][ni][r] + bv[ni];
            }
}

// ---------------------------------------------------------------------------
// Flash attention: wave-independent key chunks, zero barriers in K-loop.
// ---------------------------------------------------------------------------
#define PSTRIDE 136
#define LDS_TOTAL (4*64*PSTRIDE + 2048)

__global__ __launch_bounds__(256, 2) void attn_mfma_kernel(
    const unsigned short* __restrict__ QKV,
    const unsigned short* __restrict__ Vt,
    unsigned short* __restrict__ Aout)
{
    __shared__ __align__(16) unsigned char lds[LDS_TOTAL];

    const int tid  = threadIdx.x;
    const int lane = tid & 63;
    const int ln   = lane & 15;
    const int qd   = lane >> 4;
    const int qd4  = qd * 4;
    const int w    = tid >> 6;

    const int bx = blockIdx.x;
    const int p  = bx & 15;
    const int h  = (bx >> 4) & 15;
    const int b  = bx >> 8;

    unsigned char* Pb   = lds + w * (64 * PSTRIDE);
    float*         Oacc = (float*)lds;
    float*         mlm  = (float*)(lds + 4 * 64 * PSTRIDE);
    float*         mll  = mlm + 256;

    const unsigned short* Kh = QKV + 1024 + h * 64;
    const unsigned short* Qh = QKV + h * 64;
    const unsigned short* Vh = Vt + (size_t)((b * 16 + h) * 64) * TT;

    for (int ti = 0; ti < 2; ++ti) {
        const int qt = ti ? p : (31 - p);
        __syncthreads();

        short8 qa[4][2];
        {
            const unsigned short* Qb = Qh + (size_t)(b * TT + qt * 64) * 3072;
#pragma unroll
            for (int q4 = 0; q4 < 4; ++q4)
#pragma unroll
                for (int kk = 0; kk < 2; ++kk)
                    qa[q4][kk] = *(const short8*)(Qb + (size_t)(q4 * 16 + ln) * 3072 + kk * 32 + qd * 8);
        }

        f32x4 O[4][4];
#pragma unroll
        for (int dt = 0; dt < 4; ++dt)
#pragma unroll
            for (int q4 = 0; q4 < 4; ++q4)
                O[dt][q4] = (f32x4){0.f, 0.f, 0.f, 0.f};
        float m_i[4] = {-1e30f, -1e30f, -1e30f, -1e30f};
        float l_i[4] = {0.f, 0.f, 0.f, 0.f};

        for (int kc = w; kc <= qt; kc += 4) {
            const unsigned short* Kc = Kh + (size_t)(b * TT + kc * 64) * 3072;
            const unsigned short* Vc = Vh + kc * 64;

            short8 kf[4][2], vf[4][2];
#pragma unroll
            for (int kt = 0; kt < 4; ++kt)
#pragma unroll
                for (int kk = 0; kk < 2; ++kk)
                    kf[kt][kk] = *(const short8*)(Kc + (size_t)(kt * 16 + ln) * 3072 + kk * 32 + qd * 8);
#pragma unroll
            for (int dt = 0; dt < 4; ++dt)
#pragma unroll
                for (int kk = 0; kk < 2; ++kk)
                    vf[dt][kk] = *(const short8*)(Vc + (size_t)(dt * 16 + ln) * TT + kk * 32 + qd * 8);

            f32x4 st[4][4];
#pragma unroll
            for (int kt = 0; kt < 4; ++kt)
#pragma unroll
                for (int q4 = 0; q4 < 4; ++q4) {
                    f32x4 a = (f32x4){0.f, 0.f, 0.f, 0.f};
                    a = __builtin_amdgcn_mfma_f32_16x16x32_bf16(kf[kt][0], qa[q4][0], a, 0, 0, 0);
                    a = __builtin_amdgcn_mfma_f32_16x16x32_bf16(kf[kt][1], qa[q4][1], a, 0, 0, 0);
                    st[kt][q4] = a;
                }

            if (kc == qt) {
#pragma unroll
                for (int kt = 0; kt < 4; ++kt)
#pragma unroll
                    for (int q4 = 0; q4 < 4; ++q4)
#pragma unroll
                        for (int r = 0; r < 4; ++r)
                            if (kt * 16 + qd4 + r > q4 * 16 + ln)
                                st[kt][q4][r] = -1e30f;
            }

            float alpha[4];
#pragma unroll
            for (int q4 = 0; q4 < 4; ++q4) {
                float mx = st[0][q4][0];
#pragma unroll
                for (int kt = 0; kt < 4; ++kt)
#pragma unroll
                    for (int r = 0; r < 4; ++r)
                        mx = fmaxf(mx, st[kt][q4][r]);
                mx = fmaxf(mx, __shfl_xor(mx, 16, 64));
                mx = fmaxf(mx, __shfl_xor(mx, 32, 64));
                float mn = fmaxf(m_i[q4], mx);
                alpha[q4] = __expf(m_i[q4] - mn);
                m_i[q4] = mn;
            }
#pragma unroll
            for (int kt = 0; kt < 4; ++kt)
#pragma unroll
                for (int q4 = 0; q4 < 4; ++q4)
#pragma unroll
                    for (int r = 0; r < 4; ++r)
                        st[kt][q4][r] = __expf(st[kt][q4][r] - m_i[q4]);
#pragma unroll
            for (int q4 = 0; q4 < 4; ++q4) {
                float sm = 0.f;
#pragma unroll
                for (int kt = 0; kt < 4; ++kt)
#pragma unroll
                    for (int r = 0; r < 4; ++r)
                        sm += st[kt][q4][r];
                sm += __shfl_xor(sm, 16, 64);
                sm += __shfl_xor(sm, 32, 64);
                l_i[q4] = l_i[q4] * alpha[q4] + sm;
            }
#pragma unroll
            for (int dt = 0; dt < 4; ++dt)
#pragma unroll
                for (int q4 = 0; q4 < 4; ++q4) {
                    O[dt][q4][0] *= alpha[q4]; O[dt][q4][1] *= alpha[q4];
                    O[dt][q4][2] *= alpha[q4]; O[dt][q4][3] *= alpha[q4];
                }

#pragma unroll
            for (int kt = 0; kt < 4; ++kt)
#pragma unroll
                for (int q4 = 0; q4 < 4; ++q4) {
                    unsigned u0 = pack_bf16x2(st[kt][q4][0], st[kt][q4][1]);
                    unsigned u1 = pack_bf16x2(st[kt][q4][2], st[kt][q4][3]);
                    *(uint2*)(Pb + (q4 * 16 + ln) * PSTRIDE + kt * 32 + qd * 8) =
                        make_uint2(u0, u1);
                }

#pragma unroll
            for (int kk = 0; kk < 2; ++kk)
#pragma unroll
                for (int q4 = 0; q4 < 4; ++q4) {
                    union { struct { uint2 a, b; } u; short8 s; } y;
                    const unsigned char* yp = Pb + (q4 * 16 + ln) * PSTRIDE + kk * 64 + qd * 16;
                    y.u.a = *(const uint2*)(yp);
                    y.u.b = *(const uint2*)(yp + 8);
#pragma unroll
                    for (int dt = 0; dt < 4; ++dt)
                        O[dt][q4] = __builtin_amdgcn_mfma_f32_16x16x32_bf16(
                            vf[dt][kk], y.s, O[dt][q4], 0, 0, 0);
                }
        }

        if (qd == 0) {
#pragma unroll
            for (int q4 = 0; q4 < 4; ++q4) {
                mlm[w * 64 + q4 * 16 + ln] = m_i[q4];
                mll[w * 64 + q4 * 16 + ln] = l_i[q4];
            }
        }
        __syncthreads();

        float fac[4];
#pragma unroll
        for (int q4 = 0; q4 < 4; ++q4) {
            int q = q4 * 16 + ln;
            float m0 = mlm[q], m1 = mlm[64 + q], m2 = mlm[128 + q], m3 = mlm[192 + q];
            float M = fmaxf(fmaxf(m0, m1), fmaxf(m2, m3));
            float f0 = __expf(m0 - M), f1 = __expf(m1 - M);
            float f2 = __expf(m2 - M), f3 = __expf(m3 - M);
            float L = f0 * mll[q] + f1 * mll[64 + q] + f2 * mll[128 + q] + f3 * mll[192 + q];
            float myf = (w == 0) ? f0 : (w == 1) ? f1 : (w == 2) ? f2 : f3;
            fac[q4] = myf / L;
        }
#pragma unroll
        for (int dt = 0; dt < 4; ++dt)
#pragma unroll
            for (int q4 = 0; q4 < 4; ++q4) {
                O[dt][q4][0] *= fac[q4]; O[dt][q4][1] *= fac[q4];
                O[dt][q4][2] *= fac[q4]; O[dt][q4][3] *= fac[q4];
            }

        for (int wv = 0; wv < 4; ++wv) {
            if (w == wv) {
#pragma unroll
                for (int dt = 0; dt < 4; ++dt)
#pragma unroll
                    for (int q4 = 0; q4 < 4; ++q4) {
                        float* pp = Oacc + (q4 * 16 + ln) * 68 + dt * 16 + qd4;
                        if (wv == 0) {
                            *(f32x4*)pp = O[dt][q4];
                        } else {
                            f32x4 t = *(const f32x4*)pp;
                            t += O[dt][q4];
                            *(f32x4*)pp = t;
                        }
                    }
            }
            __syncthreads();
        }

        {
            int q = tid >> 2, dg = tid & 3;
            const float* rowp = Oacc + q * 68 + dg * 16;
            short8 s0v, s1v;
#pragma unroll
            for (int i = 0; i < 8; ++i) {
                s0v[i] = f2bf(rowp[i]);
                s1v[i] = f2bf(rowp[8 + i]);
            }
            size_t orow = (size_t)(b * TT + qt * 64 + q) * D_MODEL + h * 64 + dg * 16;
            *(short8*)(Aout + orow) = s0v;
            *(short8*)(Aout + orow + 8) = s1v;
        }
    }
}

// ---------------------------------------------------------------------------
extern "C" void kernel_launch(void* const* d_in, const int* in_sizes, int n_in,
                              void* d_out, int out_size, void* d_ws, size_t ws_size,
                              hipStream_t stream) {
    const float* x  = (const float*)d_in[0];
    const float* Wq = (const float*)d_in[2];
    const float* bq = (const float*)d_in[3];
    const float* Wk = (const float*)d_in[4];
    const float* bk = (const float*)d_in[5];
    const float* Wv = (const float*)d_in[6];
    const float* bv = (const float*)d_in[7];
    const float* Wo = (const float*)d_in[8];
    const float* bo = (const float*)d_in[9];
    float* out = (float*)d_out;

    uint8_t* w8 = (uint8_t*)d_ws;
    const size_t MB = 1024 * 1024;
    unsigned short* xb    = (unsigned short*)(w8);                 // 8 MB [4096][1024]
    unsigned short* Wqkvt = (unsigned short*)(w8 + 8 * MB);        // 6 MB [3072][1024]
    unsigned short* Wot   = (unsigned short*)(w8 + 14 * MB);       // 2 MB [1024][1024]
    float*          bqkv  = (float*)(w8 + 16 * MB);                // 12 KB
    unsigned short* QKV   = (unsigned short*)(w8 + 17 * MB);       // 24 MB [4096][3072] (V region unused)
    unsigned short* Vt    = (unsigned short*)(w8 + 41 * MB);       // 8 MB [2][16][64][2048]
    unsigned short* Aout  = (unsigned short*)(w8 + 49 * MB);       // 8 MB [4096][1024]

    prep_kernel<<<3073, 256, 0, stream>>>(x, Wq, Wk, Wv, Wo, bq, bk, bv,
                                          xb, Wqkvt, Wot, bqkv);
    gemm_mfma_kernel<<<dim3(24, 32), 256, 0, stream>>>(xb, Wqkvt, bqkv, QKV, Vt,
                                                       3072, 1024, 1024);
    attn_mfma_kernel<<<BB * N_HEADS * 16, 256, 0, stream>>>(QKV, Vt, Aout);
    gemm_mfma_n64_kernel<<<dim3(16, 32), 256, 0, stream>>>(Aout, Wot, bo, out,
                                                           1024, 1024);
}